// Round 9
// baseline (468.827 us; speedup 1.0000x reference)
//
#include <hip/hip_runtime.h>

#define N_NODES 50000
#define N_GRAPHS 512
#define N_EDGES 800000

typedef __attribute__((ext_vector_type(8))) short short8;
typedef __attribute__((ext_vector_type(8))) unsigned short ushort8;
typedef __attribute__((ext_vector_type(4))) float floatx4;

__device__ __forceinline__ float bf2f(unsigned short u) {
    union { unsigned int i; float f; } c;
    c.i = ((unsigned int)u) << 16;
    return c.f;
}
__device__ __forceinline__ unsigned short f2bf(float f) {
    union { float f; unsigned int i; } c;
    c.f = f;
    unsigned int u = c.i;
    return (unsigned short)((u + 0x7fffu + ((u >> 16) & 1u)) >> 16);
}

// async 16B global -> LDS (dest = wave-uniform base + lane*16)
__device__ __forceinline__ void g2lds16(const unsigned short* g, void* lds) {
    __builtin_amdgcn_global_load_lds(
        (const __attribute__((address_space(1))) void*)g,
        (__attribute__((address_space(3))) void*)lds, 16, 0, 0);
}

// ---------------- fused converts: x (1.6M float4) + W1/W2/W3 (40960) -------
__global__ void convert_all(const float* __restrict__ x, const float* __restrict__ W1,
                            const float* __restrict__ W2, const float* __restrict__ W3,
                            unsigned short* __restrict__ xo, unsigned short* __restrict__ o1,
                            unsigned short* __restrict__ o2, unsigned short* __restrict__ o3) {
    int i = blockIdx.x * blockDim.x + threadIdx.x;  // 0..1640959
    const float* src; unsigned short* dst; int base;
    if (i < 1600000)      { src = x;  dst = xo; base = i; }
    else {
        int j = i - 1600000;
        if (j < 8192)       { src = W1; dst = o1; base = j; }
        else if (j < 24576) { src = W2; dst = o2; base = j - 8192; }
        else if (j < 40960) { src = W3; dst = o3; base = j - 24576; }
        else return;
    }
    float4 v = ((const float4*)src)[base];
    ushort4 o;
    o.x = f2bf(v.x); o.y = f2bf(v.y); o.z = f2bf(v.z); o.w = f2bf(v.w);
    ((ushort4*)dst)[base] = o;
}

// ---------------- CSR build ----------------
__global__ void deg_hist(const int* __restrict__ dst, int* __restrict__ deg) {
    int e = blockIdx.x * blockDim.x + threadIdx.x;
    if (e < N_EDGES) atomicAdd(&deg[dst[e]], 1);
}

__global__ __launch_bounds__(1024) void scan1(const int* __restrict__ deg,
                                              int* __restrict__ rowptr,
                                              int* __restrict__ blocksum) {
    __shared__ int s[1024];
    int t = threadIdx.x;
    int i = blockIdx.x * 1024 + t;
    int v = (i < N_NODES) ? deg[i] : 0;
    s[t] = v;
    __syncthreads();
    for (int off = 1; off < 1024; off <<= 1) {
        int add = (t >= off) ? s[t - off] : 0;
        __syncthreads();
        s[t] += add;
        __syncthreads();
    }
    if (i < N_NODES) rowptr[i] = s[t] - v;  // exclusive
    if (t == 1023) blocksum[blockIdx.x] = s[t];
}

__global__ void scan2(int* __restrict__ blocksum, int nb) {
    if (threadIdx.x == 0 && blockIdx.x == 0) {
        int run = 0;
        for (int i = 0; i < nb; i++) { int v = blocksum[i]; blocksum[i] = run; run += v; }
    }
}

__global__ void scan3(int* __restrict__ rowptr, const int* __restrict__ blocksum,
                      int* __restrict__ cursor) {
    int i = blockIdx.x * blockDim.x + threadIdx.x;
    if (i < N_NODES) {
        int v = rowptr[i] + blocksum[i >> 10];
        rowptr[i] = v;
        cursor[i] = v;
    }
    if (i == 0) rowptr[N_NODES] = N_EDGES;
}

__global__ void scatter_csr(const int* __restrict__ src, const int* __restrict__ dst,
                            int* __restrict__ cursor, int* __restrict__ csr) {
    int e = blockIdx.x * blockDim.x + threadIdx.x;
    if (e < N_EDGES) {
        int pos = atomicAdd(&cursor[dst[e]], 1);
        csr[pos] = src[e];
    }
}

// ---- fused GIN layer v2: block owns 64 rows ------------------------------
// Phase 1: R5-proven gather shape, agg rows -> GLOBAL (coalesced, no LDS).
// Phase 2: MFMA GEMM on the same 64 rows (BM=64 x BN=256), A from agg
// (same-XCD L2-hot), W full-width; global_load_lds staging, fragment-order
// LDS with xor swizzle on the source side.
template <int K>
__global__ __launch_bounds__(256, 4) void gin_layer(
    const unsigned short* __restrict__ h, const int* __restrict__ rowptr,
    const int* __restrict__ csr, const unsigned short* __restrict__ W,
    const float* __restrict__ bias, unsigned short* __restrict__ agg,
    unsigned short* __restrict__ out) {
    const int KC = K / 32;
    __shared__ short8 As[256];    // 64 rows x 32 k  (4 KB)
    __shared__ short8 Ws[1024];   // 256 cols x 32 k (16 KB)

    int t = threadIdx.x;
    int rowbase = blockIdx.x * 64;

    // ---------- phase 1: gather 64 rows into agg (global) ----------
    {
        const int TPN = K / 8;       // lanes per node (16B each)
        const int NPB = 256 / TPN;   // nodes per pass
#pragma unroll
        for (int pass = 0; pass < 64 / NPB; ++pass) {
            int n = rowbase + pass * NPB + t / TPN;
            if (n < N_NODES) {
                int c8 = t % TPN;
                const ushort8* hp = (const ushort8*)h + c8;
                ushort8 s = hp[(size_t)n * TPN];
                float acc[8];
#pragma unroll
                for (int j = 0; j < 8; j++) acc[j] = bf2f(s[j]);
                int p = rowptr[n], end = rowptr[n + 1];
                for (; p + 4 <= end; p += 4) {
                    int j0 = csr[p], j1 = csr[p + 1], j2 = csr[p + 2], j3 = csr[p + 3];
                    ushort8 v0 = hp[(size_t)j0 * TPN];
                    ushort8 v1 = hp[(size_t)j1 * TPN];
                    ushort8 v2 = hp[(size_t)j2 * TPN];
                    ushort8 v3 = hp[(size_t)j3 * TPN];
#pragma unroll
                    for (int j = 0; j < 8; j++)
                        acc[j] += (bf2f(v0[j]) + bf2f(v1[j])) + (bf2f(v2[j]) + bf2f(v3[j]));
                }
                for (; p < end; ++p) {
                    int jj = csr[p];
                    ushort8 v = hp[(size_t)jj * TPN];
#pragma unroll
                    for (int j = 0; j < 8; j++) acc[j] += bf2f(v[j]);
                }
                ushort8 o;
#pragma unroll
                for (int j = 0; j < 8; j++) o[j] = f2bf(acc[j]);
                ((ushort8*)agg)[(size_t)n * TPN + c8] = o;
            }
        }
    }
    __syncthreads();  // agg stores drained (vmcnt0) before staging reads

    // ---------- phase 2: GEMM 64x256, A = agg rows (L2-hot) ----------
    int wave = t >> 6, lane = t & 63;
    int lkc = lane >> 4, lr = lane & 15;
    int rsw = lr ^ (lkc << 2);
    int rslot = lkc * 16 + rsw;

    // A staging: 1 call, mtile = wave
    int ar = rowbase + wave * 16 + rsw;
    if (ar >= N_NODES) ar = N_NODES - 1;
    char* asb = (char*)As + (size_t)(wave * 64) * 16;
    // W staging: 4 calls i, coltile = i*4 + wave
    int wr0 = (0 * 4 + wave) * 16 + rsw;
    int wr1 = (1 * 4 + wave) * 16 + rsw;
    int wr2 = (2 * 4 + wave) * 16 + rsw;
    int wr3 = (3 * 4 + wave) * 16 + rsw;
    char* wsb0 = (char*)Ws + (size_t)(0 * 256 + wave * 64) * 16;
    char* wsb1 = (char*)Ws + (size_t)(1 * 256 + wave * 64) * 16;
    char* wsb2 = (char*)Ws + (size_t)(2 * 256 + wave * 64) * 16;
    char* wsb3 = (char*)Ws + (size_t)(3 * 256 + wave * 64) * 16;

    floatx4 acc4[4][4];
#pragma unroll
    for (int i = 0; i < 4; i++)
#pragma unroll
        for (int j = 0; j < 4; j++) acc4[i][j] = (floatx4)(0.f);

    for (int k0 = 0; k0 < K; k0 += 32) {
        int ks = k0 + lkc * 8;
        g2lds16(agg + (size_t)ar * K + ks, asb);
        g2lds16(W + (size_t)wr0 * K + ks, wsb0);
        g2lds16(W + (size_t)wr1 * K + ks, wsb1);
        g2lds16(W + (size_t)wr2 * K + ks, wsb2);
        g2lds16(W + (size_t)wr3 * K + ks, wsb3);
        __syncthreads();

        short8 af[4], wf[4];
#pragma unroll
        for (int mt = 0; mt < 4; mt++) af[mt] = As[mt * 64 + rslot];
#pragma unroll
        for (int nt = 0; nt < 4; nt++) wf[nt] = Ws[(wave * 4 + nt) * 64 + rslot];
#pragma unroll
        for (int mt = 0; mt < 4; mt++)
#pragma unroll
            for (int nt = 0; nt < 4; nt++)
                acc4[mt][nt] = __builtin_amdgcn_mfma_f32_16x16x32_bf16(
                    af[mt], wf[nt], acc4[mt][nt], 0, 0, 0);
        __syncthreads();
    }

    // epilogue: C/D layout col=lane&15, row=(lane>>4)*4+reg
#pragma unroll
    for (int mt = 0; mt < 4; mt++) {
#pragma unroll
        for (int reg = 0; reg < 4; reg++) {
            int row = rowbase + mt * 16 + lkc * 4 + reg;
            if (row >= N_NODES) continue;
#pragma unroll
            for (int nt = 0; nt < 4; nt++) {
                int col = wave * 64 + nt * 16 + lr;
                float v = acc4[mt][nt][reg] + bias[col];
                out[(size_t)row * 256 + col] = f2bf(fmaxf(v, 0.f));
            }
        }
    }
}

// ------- fused mean-pool + MLP head: one block (256 thr) per graph ---------
__global__ __launch_bounds__(256) void pool_head(
    const unsigned short* __restrict__ h, const int* __restrict__ batch,
    const float* __restrict__ Wf1, const float* __restrict__ bf1,
    const float* __restrict__ Wf2, const float* __restrict__ bf2,
    float* __restrict__ out) {
    __shared__ float hg[256];
    __shared__ float hid[128];
    int g = blockIdx.x;
    int t = threadIdx.x;
    int lo = 0, hi = N_NODES;
    while (lo < hi) { int m = (lo + hi) >> 1; if (batch[m] < g) lo = m + 1; else hi = m; }
    int start = lo;
    lo = 0; hi = N_NODES;
    while (lo < hi) { int m = (lo + hi) >> 1; if (batch[m] < g + 1) lo = m + 1; else hi = m; }
    int end = lo;
    float acc = 0.f;
    for (int r = start; r < end; ++r) acc += bf2f(h[(size_t)r * 256 + t]);
    hg[t] = acc / fmaxf((float)(end - start), 1.0f);
    __syncthreads();
    if (t < 128) {
        float a1 = bf1[t];
        for (int c = 0; c < 256; c++) a1 += hg[c] * Wf1[t * 256 + c];
        hid[t] = fmaxf(a1, 0.f);
    }
    __syncthreads();
    if (t < 10) {
        float a = bf2[t];
        for (int j = 0; j < 128; j++) a += hid[j] * Wf2[t * 128 + j];
        out[g * 10 + t] = a;
    }
}

extern "C" void kernel_launch(void* const* d_in, const int* in_sizes, int n_in,
                              void* d_out, int out_size, void* d_ws, size_t ws_size,
                              hipStream_t stream) {
    const float* x   = (const float*)d_in[0];
    const int*  edge = (const int*)d_in[1];
    const int*  batch= (const int*)d_in[2];
    const float* W1  = (const float*)d_in[3];
    const float* b1  = (const float*)d_in[4];
    const float* W2  = (const float*)d_in[5];
    const float* b2  = (const float*)d_in[6];
    const float* W3  = (const float*)d_in[7];
    const float* b3  = (const float*)d_in[8];
    const float* Wf1 = (const float*)d_in[9];
    const float* bf1 = (const float*)d_in[10];
    const float* Wf2 = (const float*)d_in[11];
    const float* bf2 = (const float*)d_in[12];
    const int* src = edge;
    const int* dst = edge + N_EDGES;

    char* wsb = (char*)d_ws;
    size_t off = 0;
    auto alloc = [&](size_t bytes) { void* p = wsb + off; off += (bytes + 255) & ~(size_t)255; return p; };
    unsigned short* x_bf  = (unsigned short*)alloc((size_t)N_NODES * 128 * 2);
    unsigned short* agg_bf= (unsigned short*)alloc((size_t)N_NODES * 256 * 2);
    unsigned short* hA_bf = (unsigned short*)alloc((size_t)N_NODES * 256 * 2);
    unsigned short* hB_bf = (unsigned short*)alloc((size_t)N_NODES * 256 * 2);
    unsigned short* W1bf  = (unsigned short*)alloc(256 * 128 * 2);
    unsigned short* W2bf  = (unsigned short*)alloc(256 * 256 * 2);
    unsigned short* W3bf  = (unsigned short*)alloc(256 * 256 * 2);
    int* rowptr   = (int*)alloc((N_NODES + 4) * 4);
    int* cursor   = (int*)alloc(N_NODES * 4);
    int* deg      = (int*)alloc(N_NODES * 4);
    int* csr      = (int*)alloc(N_EDGES * 4);
    int* blocksum = (int*)alloc(64 * 4);

    const int NB_SCAN = (N_NODES + 1023) / 1024;  // 49

    // ---- CSR build (by dst) ----
    hipMemsetAsync(deg, 0, N_NODES * sizeof(int), stream);
    deg_hist<<<(N_EDGES + 255) / 256, 256, 0, stream>>>(dst, deg);
    scan1<<<NB_SCAN, 1024, 0, stream>>>(deg, rowptr, blocksum);
    scan2<<<1, 64, 0, stream>>>(blocksum, NB_SCAN);
    scan3<<<NB_SCAN, 1024, 0, stream>>>(rowptr, blocksum, cursor);
    scatter_csr<<<(N_EDGES + 255) / 256, 256, 0, stream>>>(src, dst, cursor, csr);

    // ---- converts (x + all weights, one launch) ----
    convert_all<<<(1640960 + 255) / 256, 256, 0, stream>>>(x, W1, W2, W3, x_bf, W1bf, W2bf, W3bf);

    const int NBLK = (N_NODES + 63) / 64;  // 782

    // ---- fused layers: gather(global agg) + GEMM per block ----
    gin_layer<128><<<NBLK, 256, 0, stream>>>(x_bf, rowptr, csr, W1bf, b1, agg_bf, hA_bf);
    gin_layer<256><<<NBLK, 256, 0, stream>>>(hA_bf, rowptr, csr, W2bf, b2, agg_bf, hB_bf);
    gin_layer<256><<<NBLK, 256, 0, stream>>>(hB_bf, rowptr, csr, W3bf, b3, agg_bf, hA_bf);

    // ---- fused mean pool + head ----
    pool_head<<<N_GRAPHS, 256, 0, stream>>>(hA_bf, batch, Wf1, bf1, Wf2, bf2, (float*)d_out);
}

// Round 10
// 468.514 us; speedup vs baseline: 1.0007x; 1.0007x over previous
//
#include <hip/hip_runtime.h>

#define N_NODES 50000
#define N_GRAPHS 512
#define N_EDGES 800000

typedef __attribute__((ext_vector_type(8))) short short8;
typedef __attribute__((ext_vector_type(8))) unsigned short ushort8;
typedef __attribute__((ext_vector_type(4))) float floatx4;

__device__ __forceinline__ float bf2f(unsigned short u) {
    union { unsigned int i; float f; } c;
    c.i = ((unsigned int)u) << 16;
    return c.f;
}
__device__ __forceinline__ unsigned short f2bf(float f) {
    union { float f; unsigned int i; } c;
    c.f = f;
    unsigned int u = c.i;
    return (unsigned short)((u + 0x7fffu + ((u >> 16) & 1u)) >> 16);
}

// ------- merged: deg histogram (blocks 0..3124) + bf16 converts ------------
__global__ void hist_convert(const int* __restrict__ dst, int* __restrict__ deg,
                             const float* __restrict__ x, const float* __restrict__ W1,
                             const float* __restrict__ W2, const float* __restrict__ W3,
                             unsigned short* __restrict__ xo, unsigned short* __restrict__ o1,
                             unsigned short* __restrict__ o2, unsigned short* __restrict__ o3) {
    int b = blockIdx.x;
    if (b < 3125) {
        int e = b * 256 + threadIdx.x;
        if (e < N_EDGES) atomicAdd(&deg[dst[e]], 1);
        return;
    }
    int i = (b - 3125) * 256 + threadIdx.x;  // float4 index, 0..1640959
    const float* src; unsigned short* dstp; int base;
    if (i < 1600000)      { src = x;  dstp = xo; base = i; }
    else {
        int j = i - 1600000;
        if (j < 8192)       { src = W1; dstp = o1; base = j; }
        else if (j < 24576) { src = W2; dstp = o2; base = j - 8192; }
        else if (j < 40960) { src = W3; dstp = o3; base = j - 24576; }
        else return;
    }
    float4 v = ((const float4*)src)[base];
    ushort4 o;
    o.x = f2bf(v.x); o.y = f2bf(v.y); o.z = f2bf(v.z); o.w = f2bf(v.w);
    ((ushort4*)dstp)[base] = o;
}

// ---------------- CSR scan (hierarchical, 49 blocks x 1024) ----------------
__global__ __launch_bounds__(1024) void scan1(const int* __restrict__ deg,
                                              int* __restrict__ rowptr,
                                              int* __restrict__ blocksum) {
    __shared__ int s[1024];
    int t = threadIdx.x;
    int i = blockIdx.x * 1024 + t;
    int v = (i < N_NODES) ? deg[i] : 0;
    s[t] = v;
    __syncthreads();
    for (int off = 1; off < 1024; off <<= 1) {
        int add = (t >= off) ? s[t - off] : 0;
        __syncthreads();
        s[t] += add;
        __syncthreads();
    }
    if (i < N_NODES) rowptr[i] = s[t] - v;  // exclusive within block
    if (t == 1023) blocksum[blockIdx.x] = s[t];
}

// scan3 also does the (tiny) cross-block prefix itself
__global__ __launch_bounds__(1024) void scan3(int* __restrict__ rowptr,
                                              const int* __restrict__ blocksum,
                                              int* __restrict__ cursor) {
    __shared__ int pref;
    int bid = blockIdx.x;
    if (threadIdx.x == 0) {
        int run = 0;
        for (int i = 0; i < bid; i++) run += blocksum[i];
        pref = run;
    }
    __syncthreads();
    int i = bid * 1024 + threadIdx.x;
    if (i < N_NODES) {
        int v = rowptr[i] + pref;
        rowptr[i] = v;
        cursor[i] = v;
    }
    if (i == 0) rowptr[N_NODES] = N_EDGES;
}

__global__ void scatter_csr(const int* __restrict__ src, const int* __restrict__ dst,
                            int* __restrict__ cursor, int* __restrict__ csr) {
    int e = blockIdx.x * blockDim.x + threadIdx.x;
    if (e < N_EDGES) {
        int pos = atomicAdd(&cursor[dst[e]], 1);
        csr[pos] = src[e];
    }
}

// ---- bf16 gather (R5 proven config): 16B/lane, unroll-4, no LDS -----------
template <int C>
__global__ __launch_bounds__(256) void gather_bf(const unsigned short* __restrict__ h,
                                                 const int* __restrict__ rowptr,
                                                 const int* __restrict__ csr,
                                                 unsigned short* __restrict__ agg) {
    const int TPN = C / 8;       // lanes per node (ushort8 = 16B each)
    const int NPB = 256 / TPN;
    int t = threadIdx.x;
    int n = blockIdx.x * NPB + t / TPN;
    if (n >= N_NODES) return;
    int c8 = t % TPN;
    const ushort8* hp = (const ushort8*)h + c8;
    ushort8 s = hp[(size_t)n * TPN];
    float acc[8];
#pragma unroll
    for (int j = 0; j < 8; j++) acc[j] = bf2f(s[j]);
    int p = rowptr[n], end = rowptr[n + 1];
    for (; p + 4 <= end; p += 4) {
        int j0 = csr[p], j1 = csr[p + 1], j2 = csr[p + 2], j3 = csr[p + 3];
        ushort8 v0 = hp[(size_t)j0 * TPN];
        ushort8 v1 = hp[(size_t)j1 * TPN];
        ushort8 v2 = hp[(size_t)j2 * TPN];
        ushort8 v3 = hp[(size_t)j3 * TPN];
#pragma unroll
        for (int j = 0; j < 8; j++)
            acc[j] += (bf2f(v0[j]) + bf2f(v1[j])) + (bf2f(v2[j]) + bf2f(v3[j]));
    }
    for (; p < end; ++p) {
        int jj = csr[p];
        ushort8 v = hp[(size_t)jj * TPN];
#pragma unroll
        for (int j = 0; j < 8; j++) acc[j] += bf2f(v[j]);
    }
    ushort8 o;
#pragma unroll
    for (int j = 0; j < 8; j++) o[j] = f2bf(acc[j]);
    ((ushort8*)agg)[(size_t)n * TPN + c8] = o;
}

// ---- LDS-free fragment-direct MFMA GEMM ----------------------------------
// out = relu(A[M,K]bf16 @ W[256,K]bf16^T + b) -> bf16.
// BM=64 (grid M/64), BN=256; 4 waves, wave w owns cols w*64..+63.
// Each lane loads its MFMA fragments straight from global:
//   A-frag(mt): A[rowbase + mt*16 + lr][k0 + lkc*8 .. +8]   (L2-hot, just written)
//   W-frag(nt): W[wcol + nt*16 + lr][k0 + lkc*8 .. +8]      (128KB, L2-resident)
// No LDS, no barriers; 16 independent MFMAs per k-step pipeline vs loads.
template <int K>
__global__ __launch_bounds__(256, 4) void gemm_frag(
    const unsigned short* __restrict__ A, const unsigned short* __restrict__ W,
    const float* __restrict__ bias, unsigned short* __restrict__ out, int M) {
    int t = threadIdx.x;
    int wave = t >> 6, lane = t & 63;
    int lr = lane & 15, lkc = lane >> 4;
    int rowbase = blockIdx.x * 64;
    int wcol = wave * 64;

    int ar[4];
#pragma unroll
    for (int mt = 0; mt < 4; mt++) {
        int r = rowbase + mt * 16 + lr;
        ar[mt] = (r < M) ? r : (M - 1);
    }

    floatx4 acc[4][4];
#pragma unroll
    for (int i = 0; i < 4; i++)
#pragma unroll
        for (int j = 0; j < 4; j++) acc[i][j] = (floatx4)(0.f);

#pragma unroll
    for (int k0 = 0; k0 < K; k0 += 32) {
        int ks = k0 + lkc * 8;
        short8 af[4], wf[4];
#pragma unroll
        for (int mt = 0; mt < 4; mt++)
            af[mt] = *(const short8*)(A + (size_t)ar[mt] * K + ks);
#pragma unroll
        for (int nt = 0; nt < 4; nt++)
            wf[nt] = *(const short8*)(W + (size_t)(wcol + nt * 16 + lr) * K + ks);
#pragma unroll
        for (int mt = 0; mt < 4; mt++)
#pragma unroll
            for (int nt = 0; nt < 4; nt++)
                acc[mt][nt] = __builtin_amdgcn_mfma_f32_16x16x32_bf16(
                    af[mt], wf[nt], acc[mt][nt], 0, 0, 0);
    }

    // C/D layout: col=lane&15, row=(lane>>4)*4+reg
#pragma unroll
    for (int mt = 0; mt < 4; mt++) {
#pragma unroll
        for (int reg = 0; reg < 4; reg++) {
            int row = rowbase + mt * 16 + lkc * 4 + reg;
            if (row >= M) continue;
#pragma unroll
            for (int nt = 0; nt < 4; nt++) {
                int col = wcol + nt * 16 + lr;
                float v = acc[mt][nt][reg] + bias[col];
                out[(size_t)row * 256 + col] = f2bf(fmaxf(v, 0.f));
            }
        }
    }
}

// ------- fused mean-pool + MLP head: one block (256 thr) per graph ---------
__global__ __launch_bounds__(256) void pool_head(
    const unsigned short* __restrict__ h, const int* __restrict__ batch,
    const float* __restrict__ Wf1, const float* __restrict__ bf1,
    const float* __restrict__ Wf2, const float* __restrict__ bf2,
    float* __restrict__ out) {
    __shared__ float hg[256];
    __shared__ float hid[128];
    int g = blockIdx.x;
    int t = threadIdx.x;
    int lo = 0, hi = N_NODES;
    while (lo < hi) { int m = (lo + hi) >> 1; if (batch[m] < g) lo = m + 1; else hi = m; }
    int start = lo;
    lo = 0; hi = N_NODES;
    while (lo < hi) { int m = (lo + hi) >> 1; if (batch[m] < g + 1) lo = m + 1; else hi = m; }
    int end = lo;
    float acc = 0.f;
    for (int r = start; r < end; ++r) acc += bf2f(h[(size_t)r * 256 + t]);
    hg[t] = acc / fmaxf((float)(end - start), 1.0f);
    __syncthreads();
    if (t < 128) {
        float a1 = bf1[t];
        for (int c = 0; c < 256; c++) a1 += hg[c] * Wf1[t * 256 + c];
        hid[t] = fmaxf(a1, 0.f);
    }
    __syncthreads();
    if (t < 10) {
        float a = bf2[t];
        for (int j = 0; j < 128; j++) a += hid[j] * Wf2[t * 128 + j];
        out[g * 10 + t] = a;
    }
}

extern "C" void kernel_launch(void* const* d_in, const int* in_sizes, int n_in,
                              void* d_out, int out_size, void* d_ws, size_t ws_size,
                              hipStream_t stream) {
    const float* x   = (const float*)d_in[0];
    const int*  edge = (const int*)d_in[1];
    const int*  batch= (const int*)d_in[2];
    const float* W1  = (const float*)d_in[3];
    const float* b1  = (const float*)d_in[4];
    const float* W2  = (const float*)d_in[5];
    const float* b2  = (const float*)d_in[6];
    const float* W3  = (const float*)d_in[7];
    const float* b3  = (const float*)d_in[8];
    const float* Wf1 = (const float*)d_in[9];
    const float* bf1 = (const float*)d_in[10];
    const float* Wf2 = (const float*)d_in[11];
    const float* bf2 = (const float*)d_in[12];
    const int* src = edge;
    const int* dst = edge + N_EDGES;

    char* wsb = (char*)d_ws;
    size_t off = 0;
    auto alloc = [&](size_t bytes) { void* p = wsb + off; off += (bytes + 255) & ~(size_t)255; return p; };
    unsigned short* x_bf  = (unsigned short*)alloc((size_t)N_NODES * 128 * 2);
    unsigned short* agg_bf= (unsigned short*)alloc((size_t)N_NODES * 256 * 2);
    unsigned short* hA_bf = (unsigned short*)alloc((size_t)N_NODES * 256 * 2);
    unsigned short* hB_bf = (unsigned short*)alloc((size_t)N_NODES * 256 * 2);
    unsigned short* W1bf  = (unsigned short*)alloc(256 * 128 * 2);
    unsigned short* W2bf  = (unsigned short*)alloc(256 * 256 * 2);
    unsigned short* W3bf  = (unsigned short*)alloc(256 * 256 * 2);
    int* rowptr   = (int*)alloc((N_NODES + 4) * 4);
    int* cursor   = (int*)alloc(N_NODES * 4);
    int* deg      = (int*)alloc(N_NODES * 4);
    int* csr      = (int*)alloc(N_EDGES * 4);
    int* blocksum = (int*)alloc(64 * 4);

    const int NB_SCAN = (N_NODES + 1023) / 1024;  // 49

    // ---- CSR build + converts ----
    hipMemsetAsync(deg, 0, N_NODES * sizeof(int), stream);
    hist_convert<<<3125 + 6410, 256, 0, stream>>>(dst, deg, x, W1, W2, W3,
                                                  x_bf, W1bf, W2bf, W3bf);
    scan1<<<NB_SCAN, 1024, 0, stream>>>(deg, rowptr, blocksum);
    scan3<<<NB_SCAN, 1024, 0, stream>>>(rowptr, blocksum, cursor);
    scatter_csr<<<(N_EDGES + 255) / 256, 256, 0, stream>>>(src, dst, cursor, csr);

    const int NGB = (N_NODES + 63) / 64;  // 782 gemm blocks

    // ---- layer 1 (K=128) ----
    gather_bf<128><<<(N_NODES + 15) / 16, 256, 0, stream>>>(x_bf, rowptr, csr, agg_bf);
    gemm_frag<128><<<NGB, 256, 0, stream>>>(agg_bf, W1bf, b1, hA_bf, N_NODES);

    // ---- layer 2 (K=256) ----
    gather_bf<256><<<(N_NODES + 7) / 8, 256, 0, stream>>>(hA_bf, rowptr, csr, agg_bf);
    gemm_frag<256><<<NGB, 256, 0, stream>>>(agg_bf, W2bf, b2, hB_bf, N_NODES);

    // ---- layer 3 (K=256) ----
    gather_bf<256><<<(N_NODES + 7) / 8, 256, 0, stream>>>(hB_bf, rowptr, csr, agg_bf);
    gemm_frag<256><<<NGB, 256, 0, stream>>>(agg_bf, W3bf, b3, hA_bf, N_NODES);

    // ---- fused mean pool + head ----
    pool_head<<<N_GRAPHS, 256, 0, stream>>>(hA_bf, batch, Wf1, bf1, Wf2, bf2, (float*)d_out);
}